// Round 18
// baseline (178.612 us; speedup 1.0000x reference)
//
#include <hip/hip_runtime.h>

// Fused cross-attention: out = concat(dec, softmax_e(enc·dec^T)^T-weighted enc)
// B=8, T_enc=T_dec=2048, D=512, fp32 in/out.
// R18: register-dieted 1024-thread block (16 waves = 4 waves/SIMD, 1 block/CU).
//      Wave = (tq = t-half, kj = 64-d k-slice); S8 f16 partials; f16-only Q
//      (16 regs), ctx 32, st 16 -> peak ~120 regs, fits (1024,4)'s 128 budget.
//      R16 machinery: fast-path softmax, T13 defer-max, deferred KT-write,
//      R9 load placement, XCD-pinned batch.

typedef _Float16 f16;
typedef f16 f16x8 __attribute__((ext_vector_type(8)));
typedef f16 f16x4 __attribute__((ext_vector_type(4)));
typedef f16 f16x2 __attribute__((ext_vector_type(2)));
typedef float f32x4 __attribute__((ext_vector_type(4)));

#define NB 8
#define TE 2048
#define TD 2048
#define DD 512
#define TBLK 64
#define EBLK 32
#define NCH (TE / EBLK)

// LDS layout (bytes) — audited: end 121728 < 163840
#define OKHI 0          // [32 e][512 d] f16 = 32768B, 1024B swizzled rows (QK A)
#define OKT  32768      // [512 d][40 e] f16 = 40960B, 80B rows, sig-swizzled (PV A)
#define OS8  73728      // 8 kj x [64 t][36 e] f16 = 36864B (72B rows)
#define OP   110592     // 2 x [64 t][40 e] f16 = 10240B, 80B rows
#define OPSZ 5120
#define OAL  120832     // 2 x 64 f32 alpha
#define OLL  121344     // 64 f32 l
#define OFLG 121600     // 2 x 16 u32 rescale flags
#define SMEM_BYTES 121728

__device__ __forceinline__ int swz1k(int row, int byteInRow) {
    return row * 1024 + (byteInRow ^ ((row & 7) << 4));
}

__global__ __launch_bounds__(1024, 4)
void attn_fused(const float* __restrict__ enc, const float* __restrict__ dec,
                float* __restrict__ out) {
    __shared__ __align__(16) char sm[SMEM_BYTES];
    const int tid  = threadIdx.x;
    const int b    = blockIdx.x & 7;          // XCD-pinned batch
    const int t0   = (blockIdx.x >> 3) * TBLK;
    const int lane = tid & 63;
    const int wv   = tid >> 6;                // 0..15
    const int li   = lane & 15;
    const int gi   = lane >> 4;
    const int tq   = wv & 1;                  // t-half: rows 32tq..32tq+31
    const int kj   = wv >> 1;                 // k-slice: d in [64kj, 64kj+64)
    const float L2E = 1.44269504088896f;

    const float* encB = enc + (size_t)b * TE * DD;
    const float* decB = dec + (size_t)b * TD * DD;
    float*       outB = out + (size_t)b * TD * (2 * DD);

    // staging map: c4 = d-quad 0..127, rb = e-quad 0..7 (e rows 4rb..4rb+3)
    const int c4 = tid & 127;
    const int rb = tid >> 7;

    // ---- issue K0 loads ----
    f32x4 st[4];
    #pragma unroll
    for (int i = 0; i < 4; ++i)
        st[i] = *(const f32x4*)(encB + (size_t)(4 * rb + i) * DD + 4 * c4);

    // ---- Q fragments (f16): t-half tq, d-slice kj ----
    f16x8 qF[2][2];
    #pragma unroll
    for (int kk = 0; kk < 2; ++kk)
        #pragma unroll
        for (int tl = 0; tl < 2; ++tl) {
            const float* qp = decB + (size_t)(t0 + 32 * tq + 16 * tl + li) * DD
                            + 64 * kj + 32 * kk + 8 * gi;
            f32x4 q0 = *(const f32x4*)qp;
            f32x4 q1 = *(const f32x4*)(qp + 4);
            f16x8 h;
            #pragma unroll
            for (int j = 0; j < 4; ++j) { h[j] = (f16)q0[j]; h[4 + j] = (f16)q1[j]; }
            qF[kk][tl] = h;
        }

    // ---- cvt K0 -> hvB + Khi-write(0); KT(0) written in iter 0 phase C ----
    f16x4 hvB[4];
    #pragma unroll
    for (int i = 0; i < 4; ++i) {
        f16x4 h4 = {(f16)st[i][0], (f16)st[i][1], (f16)st[i][2], (f16)st[i][3]};
        hvB[i] = h4;
        *(f16x4*)(sm + OKHI + swz1k(4 * rb + i, 8 * c4)) = h4;
    }
    // issue K1 loads
    #pragma unroll
    for (int i = 0; i < 4; ++i)
        st[i] = *(const f32x4*)(encB + (size_t)(EBLK + 4 * rb + i) * DD + 4 * c4);
    __syncthreads();

    // softmax ownership: wave owns t-cols [4wv, 4wv+4); 16 lanes/col, 2 e/lane
    const int cq   = lane & 3;
    const int erq  = lane >> 2;               // 0..15 -> e rows 2erq, 2erq+1
    const int tcol = 4 * wv + cq;
    float mrun = -1.0e30f;
    float lpart = 0.0f;

    f32x4 ctx[2][4];                          // d [32wv,32wv+32) x t [0,64)
    #pragma unroll
    for (int md = 0; md < 2; ++md)
        #pragma unroll
        for (int tt = 0; tt < 4; ++tt)
            ctx[md][tt] = (f32x4){0.f, 0.f, 0.f, 0.f};

    for (int ch = 0; ch < NCH; ++ch) {
        const int pb = ch & 1;
        const int qb = pb ^ 1;
        const bool doPV = (ch > 0);
        const bool more = (ch + 1 < NCH);

        // ---- phase A: QK(ch): wave (tq,kj) -> S[32e x 32t] partials ----
        f32x4 sacc[2][2];
        #pragma unroll
        for (int et = 0; et < 2; ++et)
            #pragma unroll
            for (int tl = 0; tl < 2; ++tl)
                sacc[et][tl] = (f32x4){0.f, 0.f, 0.f, 0.f};
        __builtin_amdgcn_s_setprio(1);
        #pragma unroll
        for (int kk = 0; kk < 2; ++kk) {
            int cb = 128 * kj + 64 * kk + 16 * gi;
            f16x8 aF[2];
            #pragma unroll
            for (int et = 0; et < 2; ++et)
                aF[et] = *(const f16x8*)(sm + OKHI + swz1k(16 * et + li, cb));
            #pragma unroll
            for (int et = 0; et < 2; ++et)
                #pragma unroll
                for (int tl = 0; tl < 2; ++tl)
                    sacc[et][tl] = __builtin_amdgcn_mfma_f32_16x16x32_f16(aF[et], qF[kk][tl], sacc[et][tl], 0, 0, 0);
        }
        __builtin_amdgcn_s_setprio(0);
        #pragma unroll
        for (int et = 0; et < 2; ++et)
            #pragma unroll
            for (int tl = 0; tl < 2; ++tl) {
                f16x4 sh = {(f16)sacc[et][tl][0], (f16)sacc[et][tl][1],
                            (f16)sacc[et][tl][2], (f16)sacc[et][tl][3]};
                *(f16x4*)(sm + OS8 + kj * 4608 + (32 * tq + 16 * tl + li) * 72
                          + (16 * et + 4 * gi) * 2) = sh;
            }
        __syncthreads();                                   // B1

        // ---- phase B: softmax(ch) ∥ PV(ch-1) ∥ Khi(ch+1) ∥ loads(ch+2) ----
        float s0 = 0.f, s1 = 0.f;
        #pragma unroll
        for (int bu = 0; bu < 8; ++bu) {
            f16x2 h = *(const f16x2*)(sm + OS8 + bu * 4608 + tcol * 72 + 4 * erq);
            s0 += (float)h[0];
            s1 += (float)h[1];
        }

        bool doR = false;
        f16x8 bP[4];
        if (doPV) {
            const uint4* fp = (const uint4*)(sm + OFLG + 64 * qb);
            uint4 f0 = fp[0], f1 = fp[1], f2 = fp[2], f3 = fp[3];
            doR = (f0.x | f0.y | f0.z | f0.w | f1.x | f1.y | f1.z | f1.w |
                   f2.x | f2.y | f2.z | f2.w | f3.x | f3.y | f3.z | f3.w) != 0;
            #pragma unroll
            for (int tt = 0; tt < 4; ++tt)
                bP[tt] = *(const f16x8*)(sm + OP + OPSZ * qb + (16 * tt + li) * 80 + 16 * gi);
        }
        // softmax(ch): fast path has zero cross-lane ops
        {
            float pml = fmaxf(s0, s1);
            bool trip = pml > mrun + 8.0f;                 // T13 defer-max
            unsigned long long bal = __ballot(trip);
            float alpha = 1.0f;
            if (bal != 0ULL) {                             // wave-uniform slow path
                float pm = pml;
                pm = fmaxf(pm, __shfl_xor(pm, 4));
                pm = fmaxf(pm, __shfl_xor(pm, 8));
                pm = fmaxf(pm, __shfl_xor(pm, 16));
                pm = fmaxf(pm, __shfl_xor(pm, 32));
                float mnew = fmaxf(mrun, pm);
                alpha = exp2f((mrun - mnew) * L2E);
                lpart *= alpha;
                mrun = mnew;
            }
            float p0 = exp2f((s0 - mrun) * L2E);
            float p1 = exp2f((s1 - mrun) * L2E);
            lpart += p0 + p1;
            f16x2 pw = {(f16)p0, (f16)p1};
            *(f16x2*)(sm + OP + OPSZ * pb + tcol * 80 + 4 * erq) = pw;
            if (erq == 0) *(float*)(sm + OAL + 256 * pb + 4 * tcol) = alpha;
            if (lane == 0) *(unsigned*)(sm + OFLG + 64 * pb + 4 * wv) = (bal != 0ULL) ? 1u : 0u;
        }
        // PV(ch-1): KT holds chunk ch-1 (written in phase C of iter ch-1)
        if (doPV) {
            if (doR) {
                float av[4];
                #pragma unroll
                for (int tt = 0; tt < 4; ++tt)
                    av[tt] = *(const float*)(sm + OAL + 256 * qb + 4 * (16 * tt + li));
                #pragma unroll
                for (int md = 0; md < 2; ++md)
                    #pragma unroll
                    for (int tt = 0; tt < 4; ++tt)
                        #pragma unroll
                        for (int r = 0; r < 4; ++r) ctx[md][tt][r] *= av[tt];
            }
            __builtin_amdgcn_s_setprio(1);
            #pragma unroll
            for (int md = 0; md < 2; ++md) {
                int dv = 32 * wv + 16 * md + li;
                int sig = ((dv >> 3) & 3) << 4;
                f16x8 a = *(const f16x8*)(sm + OKT + dv * 80 + ((16 * gi) ^ sig));
                #pragma unroll
                for (int tt = 0; tt < 4; ++tt)
                    ctx[md][tt] = __builtin_amdgcn_mfma_f32_16x16x32_f16(a, bP[tt], ctx[md][tt], 0, 0, 0);
            }
            __builtin_amdgcn_s_setprio(0);
        }
        // cvt st(ch+1) -> hvA + Khi-write(ch+1); issue loads(ch+2)
        f16x4 hvA[4];
        if (more) {
            #pragma unroll
            for (int i = 0; i < 4; ++i) {
                f16x4 h4 = {(f16)st[i][0], (f16)st[i][1], (f16)st[i][2], (f16)st[i][3]};
                hvA[i] = h4;
                *(f16x4*)(sm + OKHI + swz1k(4 * rb + i, 8 * c4)) = h4;
            }
            if (ch + 2 < NCH) {
                const float* src = encB + (size_t)(ch + 2) * EBLK * DD;
                #pragma unroll
                for (int i = 0; i < 4; ++i)
                    st[i] = *(const f32x4*)(src + (size_t)(4 * rb + i) * DD + 4 * c4);
            }
        }
        __syncthreads();                                   // B2
        // ---- phase C: KT-write(ch) from hvB ----
        #pragma unroll
        for (int k = 0; k < 4; ++k) {
            int d = 4 * c4 + k;
            int sig = ((d >> 3) & 3) << 4;
            f16x4 q4 = {hvB[0][k], hvB[1][k], hvB[2][k], hvB[3][k]};
            *(f16x4*)(sm + OKT + d * 80 + ((8 * rb) ^ sig)) = q4;
        }
        if (more) {
            #pragma unroll
            for (int i = 0; i < 4; ++i) hvB[i] = hvA[i];
        }
    }

    __syncthreads();   // KT(NCH-1) written in last phase C

    // ---- final PV(NCH-1) ----
    {
        const int qb2 = (NCH - 1) & 1;
        const uint4* fp = (const uint4*)(sm + OFLG + 64 * qb2);
        uint4 f0 = fp[0], f1 = fp[1], f2 = fp[2], f3 = fp[3];
        bool doR = (f0.x | f0.y | f0.z | f0.w | f1.x | f1.y | f1.z | f1.w |
                    f2.x | f2.y | f2.z | f2.w | f3.x | f3.y | f3.z | f3.w) != 0;
        f16x8 bP[4];
        #pragma unroll
        for (int tt = 0; tt < 4; ++tt)
            bP[tt] = *(const f16x8*)(sm + OP + OPSZ * qb2 + (16 * tt + li) * 80 + 16 * gi);
        if (doR) {
            float av[4];
            #pragma unroll
            for (int tt = 0; tt < 4; ++tt)
                av[tt] = *(const float*)(sm + OAL + 256 * qb2 + 4 * (16 * tt + li));
            #pragma unroll
            for (int md = 0; md < 2; ++md)
                #pragma unroll
                for (int tt = 0; tt < 4; ++tt)
                    #pragma unroll
                    for (int r = 0; r < 4; ++r) ctx[md][tt][r] *= av[tt];
        }
        #pragma unroll
        for (int md = 0; md < 2; ++md) {
            int dv = 32 * wv + 16 * md + li;
            int sig = ((dv >> 3) & 3) << 4;
            f16x8 a = *(const f16x8*)(sm + OKT + dv * 80 + ((16 * gi) ^ sig));
            #pragma unroll
            for (int tt = 0; tt < 4; ++tt)
                ctx[md][tt] = __builtin_amdgcn_mfma_f32_16x16x32_f16(a, bP[tt], ctx[md][tt], 0, 0, 0);
        }
    }

    // ---- epilogue: reduce per-lane l partials once, normalize, write ----
    {
        float ps = lpart;
        ps += __shfl_xor(ps, 4);
        ps += __shfl_xor(ps, 8);
        ps += __shfl_xor(ps, 16);
        ps += __shfl_xor(ps, 32);
        if (erq == 0) *(float*)(sm + OLL + 4 * tcol) = ps;
    }
    __syncthreads();
    float inv[4];
    #pragma unroll
    for (int tt = 0; tt < 4; ++tt)
        inv[tt] = 1.0f / *(const float*)(sm + OLL + 4 * (16 * tt + li));
    #pragma unroll
    for (int md = 0; md < 2; ++md)
        #pragma unroll
        for (int tt = 0; tt < 4; ++tt) {
            int t = t0 + 16 * tt + li;
            int d = 32 * wv + 16 * md + 4 * gi;
            float4 o;
            o.x = ctx[md][tt][0] * inv[tt];
            o.y = ctx[md][tt][1] * inv[tt];
            o.z = ctx[md][tt][2] * inv[tt];
            o.w = ctx[md][tt][3] * inv[tt];
            *(float4*)(outB + (size_t)t * (2 * DD) + DD + d) = o;
        }
    #pragma unroll
    for (int it = 0; it < TBLK * (DD / 4) / 1024; ++it) {
        int i = tid + it * 1024;
        int t = i >> 7, cc = i & 127;
        float4 q = ((const float4*)(decB + (size_t)(t0 + t) * DD))[cc];
        ((float4*)(outB + (size_t)(t0 + t) * (2 * DD)))[cc] = q;
    }
}

extern "C" void kernel_launch(void* const* d_in, const int* in_sizes, int n_in,
                              void* d_out, int out_size, void* d_ws, size_t ws_size,
                              hipStream_t stream) {
    const float* enc = (const float*)d_in[0];
    const float* dec = (const float*)d_in[1];
    float* out = (float*)d_out;
    dim3 grid(NB * (TD / TBLK));   // 256 blocks: b = bid&7 (XCD pin), ttile = bid>>3
    dim3 block(1024);
    attn_fused<<<grid, block, 0, stream>>>(enc, dec, out);
}

// Round 19
// 139.443 us; speedup vs baseline: 1.2809x; 1.2809x over previous
//
#include <hip/hip_runtime.h>

// Fused cross-attention: out = concat(dec, softmax_e(enc·dec^T)^T-weighted enc)
// B=8, T_enc=T_dec=2048, D=512, fp32 in/out.
// R19: R16 + KT double-buffered by chunk parity -> phase C merged into phase B
//      (KT-writes issue under PV's MFMA shadow; one serial LDS segment and the
//      post-loop barrier removed). Everything else identical to R16: (et,kq)
//      QK map, f16 S-partials, softmax fast path, T13 defer-max, R9 load
//      placement, XCD-pinned batch.

typedef _Float16 f16;
typedef f16 f16x8 __attribute__((ext_vector_type(8)));
typedef f16 f16x4 __attribute__((ext_vector_type(4)));
typedef float f32x4 __attribute__((ext_vector_type(4)));

#define NB 8
#define TE 2048
#define TD 2048
#define DD 512
#define TBLK 64
#define EBLK 32
#define NCH (TE / EBLK)

// LDS layout (bytes) — audited: end 144192 < 163840
#define OKHI 0          // [32 e][512 d] f16 = 32768B, 1024B swizzled rows (QK A)
#define OKT  32768      // 2 x [512 d][40 e] f16 = 2x40960B, 80B rows, sig-swz (PV A)
#define KTSZ 40960
#define OS4  114688     // 4 kq x [64 t][36 e] f16 = 18432B (72B rows)
#define OP   133120     // 2 x [64 t][40 e] f16 = 10240B, 80B rows
#define OPSZ 5120
#define OAL  143360     // 2 x 64 f32 alpha
#define OLL  143872     // 64 f32 l
#define OFLG 144128     // 2 x 8 u32 rescale flags
#define SMEM_BYTES 144192

__device__ __forceinline__ int swz1k(int row, int byteInRow) {
    return row * 1024 + (byteInRow ^ ((row & 7) << 4));
}

__global__ __launch_bounds__(512, 2)
void attn_fused(const float* __restrict__ enc, const float* __restrict__ dec,
                float* __restrict__ out) {
    __shared__ __align__(16) char sm[SMEM_BYTES];
    const int tid  = threadIdx.x;
    const int b    = blockIdx.x & 7;          // XCD-pinned batch
    const int t0   = (blockIdx.x >> 3) * TBLK;
    const int lane = tid & 63;
    const int wv   = tid >> 6;
    const int li   = lane & 15;
    const int gi   = lane >> 4;
    const int et   = wv & 1;                  // e-tile: e in [16et, 16et+16)
    const int kq   = wv >> 1;                 // k-slice: d in [128kq, 128kq+128)
    const float L2E = 1.44269504088896f;

    const float* encB = enc + (size_t)b * TE * DD;
    const float* decB = dec + (size_t)b * TD * DD;
    float*       outB = out + (size_t)b * TD * (2 * DD);

    // staging map: c4 = d-quad 0..127, rb = e-octet 0..3 (e rows 8rb..8rb+7)
    const int c4 = tid & 127;
    const int rb = tid >> 7;

    // ---- issue K0 loads ----
    f32x4 st[8];
    #pragma unroll
    for (int i = 0; i < 8; ++i)
        st[i] = *(const f32x4*)(encB + (size_t)(8 * rb + i) * DD + 4 * c4);

    // ---- Q fragments (f16) direct from global: all 64 t, k-slice kq ----
    f16x8 qF[4][4];
    #pragma unroll
    for (int kk = 0; kk < 4; ++kk)
        #pragma unroll
        for (int tl = 0; tl < 4; ++tl) {
            const float* qp = decB + (size_t)(t0 + 16 * tl + li) * DD
                            + 128 * kq + 32 * kk + 8 * gi;
            f32x4 q0 = *(const f32x4*)qp;
            f32x4 q1 = *(const f32x4*)(qp + 4);
            f16x8 h;
            #pragma unroll
            for (int j = 0; j < 4; ++j) { h[j] = (f16)q0[j]; h[4 + j] = (f16)q1[j]; }
            qF[kk][tl] = h;
        }

    // ---- cvt K0 -> hvB + Khi-write(0); KT(0) written in iter 0 phase B ----
    f16x4 hvB[8];
    #pragma unroll
    for (int i = 0; i < 8; ++i) {
        f16x4 h4 = {(f16)st[i][0], (f16)st[i][1], (f16)st[i][2], (f16)st[i][3]};
        hvB[i] = h4;
        *(f16x4*)(sm + OKHI + swz1k(8 * rb + i, 8 * c4)) = h4;
    }
    // issue K1 loads
    #pragma unroll
    for (int i = 0; i < 8; ++i)
        st[i] = *(const f32x4*)(encB + (size_t)(EBLK + 8 * rb + i) * DD + 4 * c4);
    __syncthreads();

    // softmax ownership: wave owns t-cols [8wv, 8wv+8); 8 lanes/col, 4 e/lane
    const int cq   = lane & 7;
    const int erq  = lane >> 3;               // 0..7 -> e rows 4erq..4erq+3
    const int tcol = 8 * wv + cq;
    float mrun = -1.0e30f;
    float lpart = 0.0f;                       // per-lane partial of l (4 e-slots)

    f32x4 ctx[4][4];                          // d [64wv,64wv+64) x t [0,64)
    #pragma unroll
    for (int md = 0; md < 4; ++md)
        #pragma unroll
        for (int tt = 0; tt < 4; ++tt)
            ctx[md][tt] = (f32x4){0.f, 0.f, 0.f, 0.f};

    for (int ch = 0; ch < NCH; ++ch) {
        const int pb = ch & 1;                // parity of chunk ch (KT/P/AL/FLG write)
        const int qb = pb ^ 1;                // parity of chunk ch-1 (PV reads)
        const bool doPV = (ch > 0);
        const bool more = (ch + 1 < NCH);

        // ---- phase A: QK(ch), S4 partial writes (f16) ----
        f32x4 sacc[4];
        #pragma unroll
        for (int tl = 0; tl < 4; ++tl)
            sacc[tl] = (f32x4){0.f, 0.f, 0.f, 0.f};
        __builtin_amdgcn_s_setprio(1);
        #pragma unroll
        for (int kk = 0; kk < 4; ++kk) {
            int cb = 256 * kq + 64 * kk + 16 * gi;
            f16x8 aF = *(const f16x8*)(sm + OKHI + swz1k(16 * et + li, cb));
            #pragma unroll
            for (int tl = 0; tl < 4; ++tl)
                sacc[tl] = __builtin_amdgcn_mfma_f32_16x16x32_f16(aF, qF[kk][tl], sacc[tl], 0, 0, 0);
        }
        __builtin_amdgcn_s_setprio(0);
        #pragma unroll
        for (int tl = 0; tl < 4; ++tl) {
            f16x4 sh = {(f16)sacc[tl][0], (f16)sacc[tl][1],
                        (f16)sacc[tl][2], (f16)sacc[tl][3]};
            *(f16x4*)(sm + OS4 + kq * 4608 + (16 * tl + li) * 72
                      + 32 * et + 8 * gi) = sh;
        }
        __syncthreads();                                   // B1

        // ---- phase B: softmax(ch) ∥ KT-write(ch) ∥ PV(ch-1) ∥ Khi(ch+1) ∥ loads ----
        f32x4 s4 = (f32x4){0.f, 0.f, 0.f, 0.f};
        #pragma unroll
        for (int bu = 0; bu < 4; ++bu) {
            f16x4 h = *(const f16x4*)(sm + OS4 + bu * 4608 + tcol * 72 + 8 * erq);
            #pragma unroll
            for (int j = 0; j < 4; ++j) s4[j] += (float)h[j];
        }

        bool doR = false;
        f16x8 bP[4];
        if (doPV) {
            const uint4* fp = (const uint4*)(sm + OFLG + 32 * qb);
            uint4 f0 = fp[0], f1 = fp[1];
            doR = (f0.x | f0.y | f0.z | f0.w | f1.x | f1.y | f1.z | f1.w) != 0;
            #pragma unroll
            for (int tt = 0; tt < 4; ++tt)
                bP[tt] = *(const f16x8*)(sm + OP + OPSZ * qb + (16 * tt + li) * 80 + 16 * gi);
        }
        // softmax(ch): fast path has zero cross-lane ops
        {
            float pml = fmaxf(fmaxf(s4[0], s4[1]), fmaxf(s4[2], s4[3]));
            bool trip = pml > mrun + 8.0f;                 // T13 defer-max
            unsigned long long bal = __ballot(trip);
            float alpha = 1.0f;
            if (bal != 0ULL) {                             // wave-uniform slow path
                float pm = pml;
                pm = fmaxf(pm, __shfl_xor(pm, 8));
                pm = fmaxf(pm, __shfl_xor(pm, 16));
                pm = fmaxf(pm, __shfl_xor(pm, 32));
                float mnew = fmaxf(mrun, pm);
                alpha = exp2f((mrun - mnew) * L2E);
                lpart *= alpha;
                mrun = mnew;
            }
            f32x4 p4;
            #pragma unroll
            for (int j = 0; j < 4; ++j) p4[j] = exp2f((s4[j] - mrun) * L2E);
            lpart += p4[0] + p4[1] + p4[2] + p4[3];
            f16x4 pw = {(f16)p4[0], (f16)p4[1], (f16)p4[2], (f16)p4[3]};
            *(f16x4*)(sm + OP + OPSZ * pb + tcol * 80 + 8 * erq) = pw;
            if (erq == 0) *(float*)(sm + OAL + 256 * pb + 4 * tcol) = alpha;
            if (lane == 0) *(unsigned*)(sm + OFLG + 32 * pb + 4 * wv) = (bal != 0ULL) ? 1u : 0u;
        }
        // KT-write(ch) from hvB into buf pb (PV reads buf qb -> no conflict;
        // PV(ch) reads buf pb only after B2 + phase A + B1)
        #pragma unroll
        for (int k = 0; k < 4; ++k) {
            int d = 4 * c4 + k;
            int sig = ((d >> 3) & 3) << 4;
            f16x8 q8 = {hvB[0][k], hvB[1][k], hvB[2][k], hvB[3][k],
                        hvB[4][k], hvB[5][k], hvB[6][k], hvB[7][k]};
            *(f16x8*)(sm + OKT + KTSZ * pb + d * 80 + ((16 * rb) ^ sig)) = q8;
        }
        // PV(ch-1): KT buf qb
        if (doPV) {
            if (doR) {
                float av[4];
                #pragma unroll
                for (int tt = 0; tt < 4; ++tt)
                    av[tt] = *(const float*)(sm + OAL + 256 * qb + 4 * (16 * tt + li));
                #pragma unroll
                for (int md = 0; md < 4; ++md)
                    #pragma unroll
                    for (int tt = 0; tt < 4; ++tt)
                        #pragma unroll
                        for (int r = 0; r < 4; ++r) ctx[md][tt][r] *= av[tt];
            }
            __builtin_amdgcn_s_setprio(1);
            #pragma unroll
            for (int md = 0; md < 4; ++md) {
                int dv = 64 * wv + 16 * md + li;
                int sig = ((dv >> 3) & 3) << 4;
                f16x8 a = *(const f16x8*)(sm + OKT + KTSZ * qb + dv * 80 + ((16 * gi) ^ sig));
                #pragma unroll
                for (int tt = 0; tt < 4; ++tt)
                    ctx[md][tt] = __builtin_amdgcn_mfma_f32_16x16x32_f16(a, bP[tt], ctx[md][tt], 0, 0, 0);
            }
            __builtin_amdgcn_s_setprio(0);
        }
        // cvt st(ch+1) -> hvA + Khi-write(ch+1); issue loads(ch+2)
        if (more) {
            f16x4 hvA[8];
            #pragma unroll
            for (int i = 0; i < 8; ++i) {
                f16x4 h4 = {(f16)st[i][0], (f16)st[i][1], (f16)st[i][2], (f16)st[i][3]};
                hvA[i] = h4;
                *(f16x4*)(sm + OKHI + swz1k(8 * rb + i, 8 * c4)) = h4;
            }
            if (ch + 2 < NCH) {
                const float* src = encB + (size_t)(ch + 2) * EBLK * DD;
                #pragma unroll
                for (int i = 0; i < 8; ++i)
                    st[i] = *(const f32x4*)(src + (size_t)(8 * rb + i) * DD + 4 * c4);
            }
            #pragma unroll
            for (int i = 0; i < 8; ++i) hvB[i] = hvA[i];
        }
        __syncthreads();                                   // B2
    }

    // ---- final PV(NCH-1): KT buf (NCH-1)&1, P/AL/FLG parity (NCH-1)&1 ----
    {
        const int qb2 = (NCH - 1) & 1;
        const uint4* fp = (const uint4*)(sm + OFLG + 32 * qb2);
        uint4 f0 = fp[0], f1 = fp[1];
        bool doR = (f0.x | f0.y | f0.z | f0.w | f1.x | f1.y | f1.z | f1.w) != 0;
        f16x8 bP[4];
        #pragma unroll
        for (int tt = 0; tt < 4; ++tt)
            bP[tt] = *(const f16x8*)(sm + OP + OPSZ * qb2 + (16 * tt + li) * 80 + 16 * gi);
        if (doR) {
            float av[4];
            #pragma unroll
            for (int tt = 0; tt < 4; ++tt)
                av[tt] = *(const float*)(sm + OAL + 256 * qb2 + 4 * (16 * tt + li));
            #pragma unroll
            for (int md = 0; md < 4; ++md)
                #pragma unroll
                for (int tt = 0; tt < 4; ++tt)
                    #pragma unroll
                    for (int r = 0; r < 4; ++r) ctx[md][tt][r] *= av[tt];
        }
        #pragma unroll
        for (int md = 0; md < 4; ++md) {
            int dv = 64 * wv + 16 * md + li;
            int sig = ((dv >> 3) & 3) << 4;
            f16x8 a = *(const f16x8*)(sm + OKT + KTSZ * qb2 + dv * 80 + ((16 * gi) ^ sig));
            #pragma unroll
            for (int tt = 0; tt < 4; ++tt)
                ctx[md][tt] = __builtin_amdgcn_mfma_f32_16x16x32_f16(a, bP[tt], ctx[md][tt], 0, 0, 0);
        }
    }

    // ---- epilogue: reduce per-lane l partials once, normalize, write ----
    {
        float ps = lpart;
        ps += __shfl_xor(ps, 8);
        ps += __shfl_xor(ps, 16);
        ps += __shfl_xor(ps, 32);
        if (erq == 0) *(float*)(sm + OLL + 4 * tcol) = ps;
    }
    __syncthreads();
    float inv[4];
    #pragma unroll
    for (int tt = 0; tt < 4; ++tt)
        inv[tt] = 1.0f / *(const float*)(sm + OLL + 4 * (16 * tt + li));
    #pragma unroll
    for (int md = 0; md < 4; ++md)
        #pragma unroll
        for (int tt = 0; tt < 4; ++tt) {
            int t = t0 + 16 * tt + li;
            int d = 64 * wv + 16 * md + 4 * gi;
            float4 o;
            o.x = ctx[md][tt][0] * inv[tt];
            o.y = ctx[md][tt][1] * inv[tt];
            o.z = ctx[md][tt][2] * inv[tt];
            o.w = ctx[md][tt][3] * inv[tt];
            *(float4*)(outB + (size_t)t * (2 * DD) + DD + d) = o;
        }
    #pragma unroll
    for (int it = 0; it < TBLK * (DD / 4) / 512; ++it) {
        int i = tid + it * 512;
        int t = i >> 7, cc = i & 127;
        float4 q = ((const float4*)(decB + (size_t)(t0 + t) * DD))[cc];
        ((float4*)(outB + (size_t)(t0 + t) * (2 * DD)))[cc] = q;
    }
}

extern "C" void kernel_launch(void* const* d_in, const int* in_sizes, int n_in,
                              void* d_out, int out_size, void* d_ws, size_t ws_size,
                              hipStream_t stream) {
    const float* enc = (const float*)d_in[0];
    const float* dec = (const float*)d_in[1];
    float* out = (float*)d_out;
    dim3 grid(NB * (TD / TBLK));   // 256 blocks: b = bid&7 (XCD pin), ttile = bid>>3
    dim3 block(512);
    attn_fused<<<grid, block, 0, stream>>>(enc, dec, out);
}

// Round 20
// 135.614 us; speedup vs baseline: 1.3171x; 1.0282x over previous
//
#include <hip/hip_runtime.h>

// Fused cross-attention: out = concat(dec, softmax_e(enc·dec^T)^T-weighted enc)
// B=8, T_enc=T_dec=2048, D=512, fp32 in/out.
// R20: R16 (best, 133us) + dec->out passthrough moved INTO the chunk loop
//      (one iteration per chunk for ch<16, issued in phase B; hides the
//      serial epilogue global phase under compute). Everything else identical
//      to R16: (et,kq) QK map, f16 S-partials, softmax fast path, T13
//      defer-max, deferred KT-write (phase C), R9 load placement, XCD pin.

typedef _Float16 f16;
typedef f16 f16x8 __attribute__((ext_vector_type(8)));
typedef f16 f16x4 __attribute__((ext_vector_type(4)));
typedef float f32x4 __attribute__((ext_vector_type(4)));

#define NB 8
#define TE 2048
#define TD 2048
#define DD 512
#define TBLK 64
#define EBLK 32
#define NCH (TE / EBLK)

// LDS layout (bytes) — audited: end 103232 < 163840
#define OKHI 0          // [32 e][512 d] f16 = 32768B, 1024B swizzled rows (QK A)
#define OKT  32768      // [512 d][40 e] f16 = 40960B, 80B rows, sig-swizzled (PV A)
#define OS4  73728      // 4 kq x [64 t][36 e] f16 = 18432B (72B rows)
#define OP   92160      // 2 x [64 t][40 e] f16 = 10240B, 80B rows
#define OPSZ 5120
#define OAL  102400     // 2 x 64 f32 alpha
#define OLL  102912     // 64 f32 l
#define OFLG 103168     // 2 x 8 u32 rescale flags
#define SMEM_BYTES 103232

__device__ __forceinline__ int swz1k(int row, int byteInRow) {
    return row * 1024 + (byteInRow ^ ((row & 7) << 4));
}

__global__ __launch_bounds__(512, 2)
void attn_fused(const float* __restrict__ enc, const float* __restrict__ dec,
                float* __restrict__ out) {
    __shared__ __align__(16) char sm[SMEM_BYTES];
    const int tid  = threadIdx.x;
    const int b    = blockIdx.x & 7;          // XCD-pinned batch
    const int t0   = (blockIdx.x >> 3) * TBLK;
    const int lane = tid & 63;
    const int wv   = tid >> 6;
    const int li   = lane & 15;
    const int gi   = lane >> 4;
    const int et   = wv & 1;                  // e-tile: e in [16et, 16et+16)
    const int kq   = wv >> 1;                 // k-slice: d in [128kq, 128kq+128)
    const float L2E = 1.44269504088896f;

    const float* encB = enc + (size_t)b * TE * DD;
    const float* decB = dec + (size_t)b * TD * DD;
    float*       outB = out + (size_t)b * TD * (2 * DD);

    // staging map: c4 = d-quad 0..127, rb = e-octet 0..3 (e rows 8rb..8rb+7)
    const int c4 = tid & 127;
    const int rb = tid >> 7;

    // ---- issue K0 loads ----
    f32x4 st[8];
    #pragma unroll
    for (int i = 0; i < 8; ++i)
        st[i] = *(const f32x4*)(encB + (size_t)(8 * rb + i) * DD + 4 * c4);

    // ---- Q fragments (f16) direct from global: all 64 t, k-slice kq ----
    f16x8 qF[4][4];
    #pragma unroll
    for (int kk = 0; kk < 4; ++kk)
        #pragma unroll
        for (int tl = 0; tl < 4; ++tl) {
            const float* qp = decB + (size_t)(t0 + 16 * tl + li) * DD
                            + 128 * kq + 32 * kk + 8 * gi;
            f32x4 q0 = *(const f32x4*)qp;
            f32x4 q1 = *(const f32x4*)(qp + 4);
            f16x8 h;
            #pragma unroll
            for (int j = 0; j < 4; ++j) { h[j] = (f16)q0[j]; h[4 + j] = (f16)q1[j]; }
            qF[kk][tl] = h;
        }

    // ---- cvt K0 -> hvB + Khi-write(0); KT(0) written in iter 0 phase C ----
    f16x4 hvB[8];
    #pragma unroll
    for (int i = 0; i < 8; ++i) {
        f16x4 h4 = {(f16)st[i][0], (f16)st[i][1], (f16)st[i][2], (f16)st[i][3]};
        hvB[i] = h4;
        *(f16x4*)(sm + OKHI + swz1k(8 * rb + i, 8 * c4)) = h4;
    }
    // issue K1 loads
    #pragma unroll
    for (int i = 0; i < 8; ++i)
        st[i] = *(const f32x4*)(encB + (size_t)(EBLK + 8 * rb + i) * DD + 4 * c4);
    __syncthreads();

    // softmax ownership: wave owns t-cols [8wv, 8wv+8); 8 lanes/col, 4 e/lane
    const int cq   = lane & 7;
    const int erq  = lane >> 3;               // 0..7 -> e rows 4erq..4erq+3
    const int tcol = 8 * wv + cq;
    float mrun = -1.0e30f;
    float lpart = 0.0f;                       // per-lane partial of l (4 e-slots)

    f32x4 ctx[4][4];                          // d [64wv,64wv+64) x t [0,64)
    #pragma unroll
    for (int md = 0; md < 4; ++md)
        #pragma unroll
        for (int tt = 0; tt < 4; ++tt)
            ctx[md][tt] = (f32x4){0.f, 0.f, 0.f, 0.f};

    for (int ch = 0; ch < NCH; ++ch) {
        const int pb = ch & 1;
        const int qb = pb ^ 1;
        const bool doPV = (ch > 0);
        const bool more = (ch + 1 < NCH);

        // ---- phase A: QK(ch), S4 partial writes (f16) ----
        f32x4 sacc[4];
        #pragma unroll
        for (int tl = 0; tl < 4; ++tl)
            sacc[tl] = (f32x4){0.f, 0.f, 0.f, 0.f};
        __builtin_amdgcn_s_setprio(1);
        #pragma unroll
        for (int kk = 0; kk < 4; ++kk) {
            int cb = 256 * kq + 64 * kk + 16 * gi;
            f16x8 aF = *(const f16x8*)(sm + OKHI + swz1k(16 * et + li, cb));
            #pragma unroll
            for (int tl = 0; tl < 4; ++tl)
                sacc[tl] = __builtin_amdgcn_mfma_f32_16x16x32_f16(aF, qF[kk][tl], sacc[tl], 0, 0, 0);
        }
        __builtin_amdgcn_s_setprio(0);
        #pragma unroll
        for (int tl = 0; tl < 4; ++tl) {
            f16x4 sh = {(f16)sacc[tl][0], (f16)sacc[tl][1],
                        (f16)sacc[tl][2], (f16)sacc[tl][3]};
            *(f16x4*)(sm + OS4 + kq * 4608 + (16 * tl + li) * 72
                      + 32 * et + 8 * gi) = sh;
        }
        __syncthreads();                                   // B1

        // ---- phase B: softmax(ch) ∥ PV(ch-1) ∥ passthrough ∥ Khi(ch+1) ∥ loads ----
        f32x4 s4 = (f32x4){0.f, 0.f, 0.f, 0.f};
        #pragma unroll
        for (int bu = 0; bu < 4; ++bu) {
            f16x4 h = *(const f16x4*)(sm + OS4 + bu * 4608 + tcol * 72 + 8 * erq);
            #pragma unroll
            for (int j = 0; j < 4; ++j) s4[j] += (float)h[j];
        }

        // dec->out passthrough, one slice per chunk (hidden under compute)
        if (ch < TBLK * (DD / 4) / 512) {
            int i = tid + ch * 512;
            int t = i >> 7, cc = i & 127;
            float4 q = ((const float4*)(decB + (size_t)(t0 + t) * DD))[cc];
            ((float4*)(outB + (size_t)(t0 + t) * (2 * DD)))[cc] = q;
        }

        bool doR = false;
        f16x8 bP[4];
        if (doPV) {
            const uint4* fp = (const uint4*)(sm + OFLG + 32 * qb);
            uint4 f0 = fp[0], f1 = fp[1];
            doR = (f0.x | f0.y | f0.z | f0.w | f1.x | f1.y | f1.z | f1.w) != 0;
            #pragma unroll
            for (int tt = 0; tt < 4; ++tt)
                bP[tt] = *(const f16x8*)(sm + OP + OPSZ * qb + (16 * tt + li) * 80 + 16 * gi);
        }
        // softmax(ch): fast path has zero cross-lane ops
        {
            float pml = fmaxf(fmaxf(s4[0], s4[1]), fmaxf(s4[2], s4[3]));
            bool trip = pml > mrun + 8.0f;                 // T13 defer-max
            unsigned long long bal = __ballot(trip);
            float alpha = 1.0f;
            if (bal != 0ULL) {                             // wave-uniform slow path
                float pm = pml;
                pm = fmaxf(pm, __shfl_xor(pm, 8));
                pm = fmaxf(pm, __shfl_xor(pm, 16));
                pm = fmaxf(pm, __shfl_xor(pm, 32));
                float mnew = fmaxf(mrun, pm);
                alpha = exp2f((mrun - mnew) * L2E);
                lpart *= alpha;
                mrun = mnew;
            }
            f32x4 p4;
            #pragma unroll
            for (int j = 0; j < 4; ++j) p4[j] = exp2f((s4[j] - mrun) * L2E);
            lpart += p4[0] + p4[1] + p4[2] + p4[3];
            f16x4 pw = {(f16)p4[0], (f16)p4[1], (f16)p4[2], (f16)p4[3]};
            *(f16x4*)(sm + OP + OPSZ * pb + tcol * 80 + 8 * erq) = pw;
            if (erq == 0) *(float*)(sm + OAL + 256 * pb + 4 * tcol) = alpha;
            if (lane == 0) *(unsigned*)(sm + OFLG + 32 * pb + 4 * wv) = (bal != 0ULL) ? 1u : 0u;
        }
        // PV(ch-1): KT holds chunk ch-1 (written in phase C of iter ch-1)
        if (doPV) {
            if (doR) {
                float av[4];
                #pragma unroll
                for (int tt = 0; tt < 4; ++tt)
                    av[tt] = *(const float*)(sm + OAL + 256 * qb + 4 * (16 * tt + li));
                #pragma unroll
                for (int md = 0; md < 4; ++md)
                    #pragma unroll
                    for (int tt = 0; tt < 4; ++tt)
                        #pragma unroll
                        for (int r = 0; r < 4; ++r) ctx[md][tt][r] *= av[tt];
            }
            __builtin_amdgcn_s_setprio(1);
            #pragma unroll
            for (int md = 0; md < 4; ++md) {
                int dv = 64 * wv + 16 * md + li;
                int sig = ((dv >> 3) & 3) << 4;
                f16x8 a = *(const f16x8*)(sm + OKT + dv * 80 + ((16 * gi) ^ sig));
                #pragma unroll
                for (int tt = 0; tt < 4; ++tt)
                    ctx[md][tt] = __builtin_amdgcn_mfma_f32_16x16x32_f16(a, bP[tt], ctx[md][tt], 0, 0, 0);
            }
            __builtin_amdgcn_s_setprio(0);
        }
        // cvt st(ch+1) -> hvA + Khi-write(ch+1); issue loads(ch+2)
        f16x4 hvA[8];
        if (more) {
            #pragma unroll
            for (int i = 0; i < 8; ++i) {
                f16x4 h4 = {(f16)st[i][0], (f16)st[i][1], (f16)st[i][2], (f16)st[i][3]};
                hvA[i] = h4;
                *(f16x4*)(sm + OKHI + swz1k(8 * rb + i, 8 * c4)) = h4;
            }
            if (ch + 2 < NCH) {
                const float* src = encB + (size_t)(ch + 2) * EBLK * DD;
                #pragma unroll
                for (int i = 0; i < 8; ++i)
                    st[i] = *(const f32x4*)(src + (size_t)(8 * rb + i) * DD + 4 * c4);
            }
        }
        __syncthreads();                                   // B2
        // ---- phase C: KT-write(ch) from hvB ----
        #pragma unroll
        for (int k = 0; k < 4; ++k) {
            int d = 4 * c4 + k;
            int sig = ((d >> 3) & 3) << 4;
            f16x8 q8 = {hvB[0][k], hvB[1][k], hvB[2][k], hvB[3][k],
                        hvB[4][k], hvB[5][k], hvB[6][k], hvB[7][k]};
            *(f16x8*)(sm + OKT + d * 80 + ((16 * rb) ^ sig)) = q8;
        }
        if (more) {
            #pragma unroll
            for (int i = 0; i < 8; ++i) hvB[i] = hvA[i];
        }
    }

    __syncthreads();   // KT(NCH-1) written in last phase C

    // ---- final PV(NCH-1) ----
    {
        const int qb2 = (NCH - 1) & 1;
        const uint4* fp = (const uint4*)(sm + OFLG + 32 * qb2);
        uint4 f0 = fp[0], f1 = fp[1];
        bool doR = (f0.x | f0.y | f0.z | f0.w | f1.x | f1.y | f1.z | f1.w) != 0;
        f16x8 bP[4];
        #pragma unroll
        for (int tt = 0; tt < 4; ++tt)
            bP[tt] = *(const f16x8*)(sm + OP + OPSZ * qb2 + (16 * tt + li) * 80 + 16 * gi);
        if (doR) {
            float av[4];
            #pragma unroll
            for (int tt = 0; tt < 4; ++tt)
                av[tt] = *(const float*)(sm + OAL + 256 * qb2 + 4 * (16 * tt + li));
            #pragma unroll
            for (int md = 0; md < 4; ++md)
                #pragma unroll
                for (int tt = 0; tt < 4; ++tt)
                    #pragma unroll
                    for (int r = 0; r < 4; ++r) ctx[md][tt][r] *= av[tt];
        }
        #pragma unroll
        for (int md = 0; md < 4; ++md) {
            int dv = 64 * wv + 16 * md + li;
            int sig = ((dv >> 3) & 3) << 4;
            f16x8 a = *(const f16x8*)(sm + OKT + dv * 80 + ((16 * gi) ^ sig));
            #pragma unroll
            for (int tt = 0; tt < 4; ++tt)
                ctx[md][tt] = __builtin_amdgcn_mfma_f32_16x16x32_f16(a, bP[tt], ctx[md][tt], 0, 0, 0);
        }
    }

    // ---- epilogue: reduce per-lane l partials once, normalize, write ----
    {
        float ps = lpart;
        ps += __shfl_xor(ps, 8);
        ps += __shfl_xor(ps, 16);
        ps += __shfl_xor(ps, 32);
        if (erq == 0) *(float*)(sm + OLL + 4 * tcol) = ps;
    }
    __syncthreads();
    float inv[4];
    #pragma unroll
    for (int tt = 0; tt < 4; ++tt)
        inv[tt] = 1.0f / *(const float*)(sm + OLL + 4 * (16 * tt + li));
    #pragma unroll
    for (int md = 0; md < 4; ++md)
        #pragma unroll
        for (int tt = 0; tt < 4; ++tt) {
            int t = t0 + 16 * tt + li;
            int d = 64 * wv + 16 * md + 4 * gi;
            float4 o;
            o.x = ctx[md][tt][0] * inv[tt];
            o.y = ctx[md][tt][1] * inv[tt];
            o.z = ctx[md][tt][2] * inv[tt];
            o.w = ctx[md][tt][3] * inv[tt];
            *(float4*)(outB + (size_t)t * (2 * DD) + DD + d) = o;
        }
}

extern "C" void kernel_launch(void* const* d_in, const int* in_sizes, int n_in,
                              void* d_out, int out_size, void* d_ws, size_t ws_size,
                              hipStream_t stream) {
    const float* enc = (const float*)d_in[0];
    const float* dec = (const float*)d_in[1];
    float* out = (float*)d_out;
    dim3 grid(NB * (TD / TBLK));   // 256 blocks: b = bid&7 (XCD pin), ttile = bid>>3
    dim3 block(512);
    attn_fused<<<grid, block, 0, stream>>>(enc, dec, out);
}

// Round 21
// 132.875 us; speedup vs baseline: 1.3442x; 1.0206x over previous
//
#include <hip/hip_runtime.h>

// Fused cross-attention: out = concat(dec, softmax_e(enc·dec^T)^T-weighted enc)
// B=8, T_enc=T_dec=2048, D=512, fp32 in/out.
// FINAL (= R16, best measured: 133.0 us, absmax 0.0586):
//   - flash-style chunk loop (EBLK=32), TBLK=64, 512 thr, 1 blk/CU
//   - f16 QK with fp32 MFMA accum; (et,kq) wave map (no aF duplication)
//   - f16 S-partial buffers (S4), f16 KT (sig-swizzled), swizzled Khi
//   - fast-path online softmax (zero cross-lane ops on the common path),
//     T13 defer-max (THR=8), per-lane partial l reduced once in epilogue
//   - 2-barrier pipeline w/ deferred KT-write (phase C), prefetch depth 2
//   - XCD-pinned batch (b = bid&7)
// Session ladder: 381 -> 304 -> 289 -> 171 -> 145 -> 136.5 -> 134.6 -> 133.0 us.
// Plateau: latency-bound at 2 waves/SIMD (no pipe >50%); 4 waves/SIMD spills
// (3x confirmed); schedule/LDS/occupancy levers exhausted.

typedef _Float16 f16;
typedef f16 f16x8 __attribute__((ext_vector_type(8)));
typedef f16 f16x4 __attribute__((ext_vector_type(4)));
typedef float f32x4 __attribute__((ext_vector_type(4)));

#define NB 8
#define TE 2048
#define TD 2048
#define DD 512
#define TBLK 64
#define EBLK 32
#define NCH (TE / EBLK)

// LDS layout (bytes) — audited: end 103232 < 163840
#define OKHI 0          // [32 e][512 d] f16 = 32768B, 1024B swizzled rows (QK A)
#define OKT  32768      // [512 d][40 e] f16 = 40960B, 80B rows, sig-swizzled (PV A)
#define OS4  73728      // 4 kq x [64 t][36 e] f16 = 18432B (72B rows)
#define OP   92160      // 2 x [64 t][40 e] f16 = 10240B, 80B rows
#define OPSZ 5120
#define OAL  102400     // 2 x 64 f32 alpha
#define OLL  102912     // 64 f32 l
#define OFLG 103168     // 2 x 8 u32 rescale flags
#define SMEM_BYTES 103232

__device__ __forceinline__ int swz1k(int row, int byteInRow) {
    return row * 1024 + (byteInRow ^ ((row & 7) << 4));
}

__global__ __launch_bounds__(512, 2)
void attn_fused(const float* __restrict__ enc, const float* __restrict__ dec,
                float* __restrict__ out) {
    __shared__ __align__(16) char sm[SMEM_BYTES];
    const int tid  = threadIdx.x;
    const int b    = blockIdx.x & 7;          // XCD-pinned batch
    const int t0   = (blockIdx.x >> 3) * TBLK;
    const int lane = tid & 63;
    const int wv   = tid >> 6;
    const int li   = lane & 15;
    const int gi   = lane >> 4;
    const int et   = wv & 1;                  // e-tile: e in [16et, 16et+16)
    const int kq   = wv >> 1;                 // k-slice: d in [128kq, 128kq+128)
    const float L2E = 1.44269504088896f;

    const float* encB = enc + (size_t)b * TE * DD;
    const float* decB = dec + (size_t)b * TD * DD;
    float*       outB = out + (size_t)b * TD * (2 * DD);

    // staging map: c4 = d-quad 0..127, rb = e-octet 0..3 (e rows 8rb..8rb+7)
    const int c4 = tid & 127;
    const int rb = tid >> 7;

    // ---- issue K0 loads ----
    f32x4 st[8];
    #pragma unroll
    for (int i = 0; i < 8; ++i)
        st[i] = *(const f32x4*)(encB + (size_t)(8 * rb + i) * DD + 4 * c4);

    // ---- Q fragments (f16) direct from global: all 64 t, k-slice kq ----
    f16x8 qF[4][4];
    #pragma unroll
    for (int kk = 0; kk < 4; ++kk)
        #pragma unroll
        for (int tl = 0; tl < 4; ++tl) {
            const float* qp = decB + (size_t)(t0 + 16 * tl + li) * DD
                            + 128 * kq + 32 * kk + 8 * gi;
            f32x4 q0 = *(const f32x4*)qp;
            f32x4 q1 = *(const f32x4*)(qp + 4);
            f16x8 h;
            #pragma unroll
            for (int j = 0; j < 4; ++j) { h[j] = (f16)q0[j]; h[4 + j] = (f16)q1[j]; }
            qF[kk][tl] = h;
        }

    // ---- cvt K0 -> hvB + Khi-write(0); KT(0) written in iter 0 phase C ----
    f16x4 hvB[8];
    #pragma unroll
    for (int i = 0; i < 8; ++i) {
        f16x4 h4 = {(f16)st[i][0], (f16)st[i][1], (f16)st[i][2], (f16)st[i][3]};
        hvB[i] = h4;
        *(f16x4*)(sm + OKHI + swz1k(8 * rb + i, 8 * c4)) = h4;
    }
    // issue K1 loads
    #pragma unroll
    for (int i = 0; i < 8; ++i)
        st[i] = *(const f32x4*)(encB + (size_t)(EBLK + 8 * rb + i) * DD + 4 * c4);
    __syncthreads();

    // softmax ownership: wave owns t-cols [8wv, 8wv+8); 8 lanes/col, 4 e/lane
    const int cq   = lane & 7;
    const int erq  = lane >> 3;               // 0..7 -> e rows 4erq..4erq+3
    const int tcol = 8 * wv + cq;
    float mrun = -1.0e30f;
    float lpart = 0.0f;                       // per-lane partial of l (4 e-slots)

    f32x4 ctx[4][4];                          // d [64wv,64wv+64) x t [0,64)
    #pragma unroll
    for (int md = 0; md < 4; ++md)
        #pragma unroll
        for (int tt = 0; tt < 4; ++tt)
            ctx[md][tt] = (f32x4){0.f, 0.f, 0.f, 0.f};

    for (int ch = 0; ch < NCH; ++ch) {
        const int pb = ch & 1;
        const int qb = pb ^ 1;
        const bool doPV = (ch > 0);
        const bool more = (ch + 1 < NCH);

        // ---- phase A: QK(ch), S4 partial writes (f16) ----
        f32x4 sacc[4];
        #pragma unroll
        for (int tl = 0; tl < 4; ++tl)
            sacc[tl] = (f32x4){0.f, 0.f, 0.f, 0.f};
        __builtin_amdgcn_s_setprio(1);
        #pragma unroll
        for (int kk = 0; kk < 4; ++kk) {
            int cb = 256 * kq + 64 * kk + 16 * gi;
            f16x8 aF = *(const f16x8*)(sm + OKHI + swz1k(16 * et + li, cb));
            #pragma unroll
            for (int tl = 0; tl < 4; ++tl)
                sacc[tl] = __builtin_amdgcn_mfma_f32_16x16x32_f16(aF, qF[kk][tl], sacc[tl], 0, 0, 0);
        }
        __builtin_amdgcn_s_setprio(0);
        #pragma unroll
        for (int tl = 0; tl < 4; ++tl) {
            f16x4 sh = {(f16)sacc[tl][0], (f16)sacc[tl][1],
                        (f16)sacc[tl][2], (f16)sacc[tl][3]};
            *(f16x4*)(sm + OS4 + kq * 4608 + (16 * tl + li) * 72
                      + 32 * et + 8 * gi) = sh;
        }
        __syncthreads();                                   // B1

        // ---- phase B: softmax(ch) ∥ PV(ch-1) ∥ Khi(ch+1) ∥ loads(ch+2) ----
        f32x4 s4 = (f32x4){0.f, 0.f, 0.f, 0.f};
        #pragma unroll
        for (int bu = 0; bu < 4; ++bu) {
            f16x4 h = *(const f16x4*)(sm + OS4 + bu * 4608 + tcol * 72 + 8 * erq);
            #pragma unroll
            for (int j = 0; j < 4; ++j) s4[j] += (float)h[j];
        }

        bool doR = false;
        f16x8 bP[4];
        if (doPV) {
            const uint4* fp = (const uint4*)(sm + OFLG + 32 * qb);
            uint4 f0 = fp[0], f1 = fp[1];
            doR = (f0.x | f0.y | f0.z | f0.w | f1.x | f1.y | f1.z | f1.w) != 0;
            #pragma unroll
            for (int tt = 0; tt < 4; ++tt)
                bP[tt] = *(const f16x8*)(sm + OP + OPSZ * qb + (16 * tt + li) * 80 + 16 * gi);
        }
        // softmax(ch): fast path has zero cross-lane ops
        {
            float pml = fmaxf(fmaxf(s4[0], s4[1]), fmaxf(s4[2], s4[3]));
            bool trip = pml > mrun + 8.0f;                 // T13 defer-max
            unsigned long long bal = __ballot(trip);
            float alpha = 1.0f;
            if (bal != 0ULL) {                             // wave-uniform slow path
                float pm = pml;
                pm = fmaxf(pm, __shfl_xor(pm, 8));
                pm = fmaxf(pm, __shfl_xor(pm, 16));
                pm = fmaxf(pm, __shfl_xor(pm, 32));
                float mnew = fmaxf(mrun, pm);
                alpha = exp2f((mrun - mnew) * L2E);
                lpart *= alpha;
                mrun = mnew;
            }
            f32x4 p4;
            #pragma unroll
            for (int j = 0; j < 4; ++j) p4[j] = exp2f((s4[j] - mrun) * L2E);
            lpart += p4[0] + p4[1] + p4[2] + p4[3];
            f16x4 pw = {(f16)p4[0], (f16)p4[1], (f16)p4[2], (f16)p4[3]};
            *(f16x4*)(sm + OP + OPSZ * pb + tcol * 80 + 8 * erq) = pw;
            if (erq == 0) *(float*)(sm + OAL + 256 * pb + 4 * tcol) = alpha;
            if (lane == 0) *(unsigned*)(sm + OFLG + 32 * pb + 4 * wv) = (bal != 0ULL) ? 1u : 0u;
        }
        // PV(ch-1): KT holds chunk ch-1 (written in phase C of iter ch-1)
        if (doPV) {
            if (doR) {
                float av[4];
                #pragma unroll
                for (int tt = 0; tt < 4; ++tt)
                    av[tt] = *(const float*)(sm + OAL + 256 * qb + 4 * (16 * tt + li));
                #pragma unroll
                for (int md = 0; md < 4; ++md)
                    #pragma unroll
                    for (int tt = 0; tt < 4; ++tt)
                        #pragma unroll
                        for (int r = 0; r < 4; ++r) ctx[md][tt][r] *= av[tt];
            }
            __builtin_amdgcn_s_setprio(1);
            #pragma unroll
            for (int md = 0; md < 4; ++md) {
                int dv = 64 * wv + 16 * md + li;
                int sig = ((dv >> 3) & 3) << 4;
                f16x8 a = *(const f16x8*)(sm + OKT + dv * 80 + ((16 * gi) ^ sig));
                #pragma unroll
                for (int tt = 0; tt < 4; ++tt)
                    ctx[md][tt] = __builtin_amdgcn_mfma_f32_16x16x32_f16(a, bP[tt], ctx[md][tt], 0, 0, 0);
            }
            __builtin_amdgcn_s_setprio(0);
        }
        // cvt st(ch+1) -> hvA + Khi-write(ch+1); issue loads(ch+2)
        f16x4 hvA[8];
        if (more) {
            #pragma unroll
            for (int i = 0; i < 8; ++i) {
                f16x4 h4 = {(f16)st[i][0], (f16)st[i][1], (f16)st[i][2], (f16)st[i][3]};
                hvA[i] = h4;
                *(f16x4*)(sm + OKHI + swz1k(8 * rb + i, 8 * c4)) = h4;
            }
            if (ch + 2 < NCH) {
                const float* src = encB + (size_t)(ch + 2) * EBLK * DD;
                #pragma unroll
                for (int i = 0; i < 8; ++i)
                    st[i] = *(const f32x4*)(src + (size_t)(8 * rb + i) * DD + 4 * c4);
            }
        }
        __syncthreads();                                   // B2
        // ---- phase C: KT-write(ch) from hvB ----
        #pragma unroll
        for (int k = 0; k < 4; ++k) {
            int d = 4 * c4 + k;
            int sig = ((d >> 3) & 3) << 4;
            f16x8 q8 = {hvB[0][k], hvB[1][k], hvB[2][k], hvB[3][k],
                        hvB[4][k], hvB[5][k], hvB[6][k], hvB[7][k]};
            *(f16x8*)(sm + OKT + d * 80 + ((16 * rb) ^ sig)) = q8;
        }
        if (more) {
            #pragma unroll
            for (int i = 0; i < 8; ++i) hvB[i] = hvA[i];
        }
    }

    __syncthreads();   // KT(NCH-1) written in last phase C

    // ---- final PV(NCH-1) ----
    {
        const int qb2 = (NCH - 1) & 1;
        const uint4* fp = (const uint4*)(sm + OFLG + 32 * qb2);
        uint4 f0 = fp[0], f1 = fp[1];
        bool doR = (f0.x | f0.y | f0.z | f0.w | f1.x | f1.y | f1.z | f1.w) != 0;
        f16x8 bP[4];
        #pragma unroll
        for (int tt = 0; tt < 4; ++tt)
            bP[tt] = *(const f16x8*)(sm + OP + OPSZ * qb2 + (16 * tt + li) * 80 + 16 * gi);
        if (doR) {
            float av[4];
            #pragma unroll
            for (int tt = 0; tt < 4; ++tt)
                av[tt] = *(const float*)(sm + OAL + 256 * qb2 + 4 * (16 * tt + li));
            #pragma unroll
            for (int md = 0; md < 4; ++md)
                #pragma unroll
                for (int tt = 0; tt < 4; ++tt)
                    #pragma unroll
                    for (int r = 0; r < 4; ++r) ctx[md][tt][r] *= av[tt];
        }
        #pragma unroll
        for (int md = 0; md < 4; ++md) {
            int dv = 64 * wv + 16 * md + li;
            int sig = ((dv >> 3) & 3) << 4;
            f16x8 a = *(const f16x8*)(sm + OKT + dv * 80 + ((16 * gi) ^ sig));
            #pragma unroll
            for (int tt = 0; tt < 4; ++tt)
                ctx[md][tt] = __builtin_amdgcn_mfma_f32_16x16x32_f16(a, bP[tt], ctx[md][tt], 0, 0, 0);
        }
    }

    // ---- epilogue: reduce per-lane l partials once, normalize, write ----
    {
        float ps = lpart;
        ps += __shfl_xor(ps, 8);
        ps += __shfl_xor(ps, 16);
        ps += __shfl_xor(ps, 32);
        if (erq == 0) *(float*)(sm + OLL + 4 * tcol) = ps;
    }
    __syncthreads();
    float inv[4];
    #pragma unroll
    for (int tt = 0; tt < 4; ++tt)
        inv[tt] = 1.0f / *(const float*)(sm + OLL + 4 * (16 * tt + li));
    #pragma unroll
    for (int md = 0; md < 4; ++md)
        #pragma unroll
        for (int tt = 0; tt < 4; ++tt) {
            int t = t0 + 16 * tt + li;
            int d = 64 * wv + 16 * md + 4 * gi;
            float4 o;
            o.x = ctx[md][tt][0] * inv[tt];
            o.y = ctx[md][tt][1] * inv[tt];
            o.z = ctx[md][tt][2] * inv[tt];
            o.w = ctx[md][tt][3] * inv[tt];
            *(float4*)(outB + (size_t)t * (2 * DD) + DD + d) = o;
        }
    #pragma unroll
    for (int it = 0; it < TBLK * (DD / 4) / 512; ++it) {
        int i = tid + it * 512;
        int t = i >> 7, cc = i & 127;
        float4 q = ((const float4*)(decB + (size_t)(t0 + t) * DD))[cc];
        ((float4*)(outB + (size_t)(t0 + t) * (2 * DD)))[cc] = q;
    }
}

extern "C" void kernel_launch(void* const* d_in, const int* in_sizes, int n_in,
                              void* d_out, int out_size, void* d_ws, size_t ws_size,
                              hipStream_t stream) {
    const float* enc = (const float*)d_in[0];
    const float* dec = (const float*)d_in[1];
    float* out = (float*)d_out;
    dim3 grid(NB * (TD / TBLK));   // 256 blocks: b = bid&7 (XCD pin), ttile = bid>>3
    dim3 block(512);
    attn_fused<<<grid, block, 0, stream>>>(enc, dec, out);
}